// Round 9
// baseline (133.436 us; speedup 1.0000x reference)
//
#include <hip/hip_runtime.h>
#include <hip/hip_bf16.h>
#include <hip/hip_fp16.h>

// ModulatedDeformConv2d forward: f16 NHWC x, XCD-swizzled,
// producer/consumer wave-specialized fused sample+MFMA.
// R18 = R17 + (1) consumer A-fragments for ALL 9 taps hoisted into
// registers at init (18 frags = 72 VGPR): consumer per-tap VMEM -> 0,
// total VMEM 40 -> 32 instr/tap on the confirmed address-pipe bound;
// (2) LDS param tables shrunk (pidx -> ushort4 packed linear corner
// indices, pwts -> packed half4): block LDS 36864 -> 27648 B so 4 blocks
// co-reside per CU (R17 ran at ~2 -> poor pipe overlap, Occ 49%).
// x[8,64,128,128] f32, offset[8,18,128,128], mask[8,9,128,128],
// weight[64,64,3,3], bias[64]; out[8,64,128,128] f32.

constexpr int B    = 8;
constexpr int C    = 64;
constexpr int H    = 128;
constexpr int W    = 128;
constexpr int COUT = 64;
constexpr int K2   = 9;
constexpr int HW   = H * W;
constexpr int TPX  = 64;   // pixels per tile

typedef __attribute__((ext_vector_type(8))) short    short8;
typedef __attribute__((ext_vector_type(8))) _Float16 f16x8;
typedef __attribute__((ext_vector_type(4))) float    f32x4;

// LDS tile row: 64 ch padded to 72 halves (144 B).
constexpr int LDSS = 72;

// Raw workgroup barrier: drain LDS ops only (no vmcnt(0) drain).
#define LDS_BARRIER() asm volatile("s_waitcnt lgkmcnt(0)\n\ts_barrier" ::: "memory")

// ---------- x: NCHW f32 -> NHWC f16 ----------
__global__ __launch_bounds__(256) void transpose_x_kernel(
    const float* __restrict__ x, short* __restrict__ xt) {
    __shared__ float tbuf[64][65];
    const int blk  = blockIdx.x;          // B * (HW/64) = 2048
    const int b    = blk >> 8;
    const int hwb  = (blk & 255) * 64;
    const int lane = threadIdx.x & 63;
    const int grp  = threadIdx.x >> 6;    // 0..3
    const float* xb = x + (size_t)b * C * HW;
#pragma unroll
    for (int r = 0; r < 16; ++r) {
        const int c = grp * 16 + r;
        tbuf[c][lane] = xb[c * HW + hwb + lane];   // coalesced along hw
    }
    __syncthreads();
    short* xo = xt + (size_t)b * HW * C;
#pragma unroll
    for (int r = 0; r < 16; ++r) {
        const int hw_l = grp * 16 + r;
        union { __half h; short s; } u;
        u.h = __float2half(tbuf[lane][hw_l]);
        xo[(size_t)(hwb + hw_l) * C + lane] = u.s;  // coalesced along c
    }
}

// ---------- weight[o][c][3][3] f32 -> A-fragment-ordered f16 ----------
// wfrag[(k*8 + kk*4 + mt)*64 + lane][j] = f16( w[m][c][k] )
//   m = mt*16 + (lane&15), q = lane>>4, c = kk*32 + q*8 + j
__global__ __launch_bounds__(256) void pack_w_kernel(
    const float* __restrict__ w, short* __restrict__ wfrag) {
    int id = blockIdx.x * blockDim.x + threadIdx.x;
    if (id >= COUT * C * K2) return;
    const int j    = id & 7;
    const int lane = (id >> 3) & 63;
    const int mt   = (id >> 9) & 3;
    const int kk   = (id >> 11) & 1;
    const int k    = id >> 12;
    const int m    = mt * 16 + (lane & 15);
    const int q    = lane >> 4;
    const int c    = kk * 32 + q * 8 + j;
    union { __half h; short s; } u;
    u.h = __float2half(w[(m * C + c) * K2 + k]);
    wfrag[id] = u.s;
}

// ---------- producer/consumer fused kernel ----------
// grid 2048: b = wg&7 (XCD round-robin -> per-XCD-L2-resident f16 x),
// t = wg>>3 -> (ho, 64-px half-row). 512 threads = 8 waves.
__global__ __launch_bounds__(512, 4) void mdcn_pc_kernel(
    const short* __restrict__ xt,      // [B][H][W][C] f16
    const float* __restrict__ offset,
    const float* __restrict__ mask,
    const short* __restrict__ wfrag,
    const float* __restrict__ bias,
    float* __restrict__ out) {

    __shared__ short   smem[2][TPX * LDSS];  // 2 x 9216 B
    __shared__ ushort4 pidx[K2 * TPX];       // 4608 B: 4 corner linear indices
    __shared__ uint2   pwts[K2 * TPX];       // 4608 B: 4 blend wts as half4

    const int wg   = blockIdx.x;
    const int b    = wg & 7;
    const int t    = wg >> 3;                // 0..255
    const int ho   = t >> 1;
    const int px0  = (t & 1) * TPX;

    const int tid  = threadIdx.x;
    const int wave = tid >> 6;

    // ---- precompute ALL taps' sampling params (one thread per (tap,px)) ----
    for (int f = tid; f < K2 * TPX; f += 512) {
        const int k = f >> 6;                // tap
        const int i = f & 63;                // tile-local pixel
        const int wo = px0 + i;
        const int ky = k / 3, kx = k % 3;
        const float dx = offset[(((size_t)b * 2 * K2 + 2 * k    ) * H + ho) * W + wo];
        const float dy = offset[(((size_t)b * 2 * K2 + 2 * k + 1) * H + ho) * W + wo];
        const float mm = mask  [(((size_t)b * K2     + k        ) * H + ho) * W + wo];
        const float py = (float)(ho - 1 + ky) + dy;
        const float px = (float)(wo - 1 + kx) + dx;
        const float y0f = floorf(py), x0f = floorf(px);
        const float wy1 = py - y0f,   wx1 = px - x0f;
        const float wy0 = 1.0f - wy1, wx0 = 1.0f - wx1;
        const int iy0 = (int)y0f, ix0 = (int)x0f;
        const int iy1 = iy0 + 1,  ix1 = ix0 + 1;
        const bool vy0 = (iy0 >= 0) & (iy0 < H);
        const bool vy1 = (iy1 >= 0) & (iy1 < H);
        const bool vx0 = (ix0 >= 0) & (ix0 < W);
        const bool vx1 = (ix1 >= 0) & (ix1 < W);
        const float w00 = (vy0 & vx0) ? wy0 * wx0 * mm : 0.0f;
        const float w01 = (vy0 & vx1) ? wy0 * wx1 * mm : 0.0f;
        const float w10 = (vy1 & vx0) ? wy1 * wx0 * mm : 0.0f;
        const float w11 = (vy1 & vx1) ? wy1 * wx1 * mm : 0.0f;
        union { __half2 h2; unsigned u; } p01, p23;
        p01.h2 = __floats2half2_rn(w00, w01);
        p23.h2 = __floats2half2_rn(w10, w11);
        const int cy0 = min(max(iy0, 0), H - 1);
        const int cy1 = min(max(iy1, 0), H - 1);
        const int cx0 = min(max(ix0, 0), W - 1);
        const int cx1 = min(max(ix1, 0), W - 1);
        // linear pixel indices (< 16384) fit u16; producer shifts <<7 for bytes
        ushort4 bv;
        bv.x = (unsigned short)(cy0 * W + cx0);
        bv.y = (unsigned short)(cy0 * W + cx1);
        bv.z = (unsigned short)(cy1 * W + cx0);
        bv.w = (unsigned short)(cy1 * W + cx1);
        pidx[f] = bv;
        pwts[f] = uint2{p01.u, p23.u};
    }
    __syncthreads();                         // init barrier (full fence, once)

    if (wave < 4) {
        // ================= PRODUCER: sample -> LDS =================
        const int spx = tid >> 2;            // 0..63 pixel in tile
        const int cq  = (tid & 3) * 16;      // 16-channel quarter
        const char* xb =
            (const char*)(xt + (size_t)b * HW * C) + cq * 2;

        for (int k = 0; k < K2; ++k) {
            const ushort4 bi = pidx[k * 64 + spx];   // ds_read_b64 (4-px bcast)
            const uint2   wu = pwts[k * 64 + spx];   // ds_read_b64
            union HU { unsigned u; __half2 h2; };
            HU t01{wu.x}, t23{wu.y};
            const __half2 w0 = __half2half2(__low2half (t01.h2));
            const __half2 w1 = __half2half2(__high2half(t01.h2));
            const __half2 w2 = __half2half2(__low2half (t23.h2));
            const __half2 w3 = __half2half2(__high2half(t23.h2));
            const short* s00 = (const short*)(xb + ((int)bi.x << 7));
            const short* s01 = (const short*)(xb + ((int)bi.y << 7));
            const short* s10 = (const short*)(xb + ((int)bi.z << 7));
            const short* s11 = (const short*)(xb + ((int)bi.w << 7));

            short* dst = &smem[k & 1][spx * LDSS + cq];
#pragma unroll
            for (int h = 0; h < 2; ++h) {    // two 8-channel halves
                union U8 { short8 s; __half2 h2[4]; };
                const U8 g00{*(const short8*)(s00 + h * 8)};
                const U8 g01{*(const short8*)(s01 + h * 8)};
                const U8 g10{*(const short8*)(s10 + h * 8)};
                const U8 g11{*(const short8*)(s11 + h * 8)};
                U8 rr;
#pragma unroll
                for (int p = 0; p < 4; ++p) {
                    rr.h2[p] = __hfma2(g11.h2[p], w3,
                               __hfma2(g10.h2[p], w2,
                               __hfma2(g01.h2[p], w1,
                               __hmul2(g00.h2[p], w0))));
                }
                *(short8*)(dst + h * 8) = rr.s;
            }
            LDS_BARRIER();                   // tile k ready (lgkm drain only)
        }
    } else {
        // ====== CONSUMER: output-channel-partitioned, zero per-tap VMEM ======
        // wave w owns outputs [16w, 16w+16) for ALL 64 pixels.
        const int w    = wave - 4;           // 0..3 output quarter
        const int lane = tid & 63;
        const int col  = lane & 15;
        const int q    = lane >> 4;
        const f16x8* wf = (const f16x8*)wfrag;

        // hoist ALL 9 taps' A-fragments (this wave's mt=w slice): 18 frags.
        f16x8 af[K2][2];
#pragma unroll
        for (int k = 0; k < K2; ++k)
#pragma unroll
            for (int kk = 0; kk < 2; ++kk)
                af[k][kk] = wf[(k * 8 + kk * 4 + w) * 64 + lane];

        f32x4 acc[4];
#pragma unroll
        for (int nt = 0; nt < 4; ++nt) acc[nt] = (f32x4)0.0f;

#pragma unroll
        for (int k = 0; k < K2; ++k) {
            LDS_BARRIER();                   // wait tile k
#pragma unroll
            for (int kk = 0; kk < 2; ++kk) {
#pragma unroll
                for (int nt = 0; nt < 4; ++nt) {
                    const f16x8 bfrag = *(const f16x8*)(
                        &smem[k & 1][(nt * 16 + col) * LDSS + kk * 32 + q * 8]);
                    acc[nt] = __builtin_amdgcn_mfma_f32_16x16x32_f16(
                        af[k][kk], bfrag, acc[nt], 0, 0, 0);
                }
            }
        }

        // ---- epilogue: D row=(q*4+r) -> o = w*16+q*4+r, col -> px ----
#pragma unroll
        for (int nt = 0; nt < 4; ++nt) {
            const int wo = px0 + nt * 16 + col;
#pragma unroll
            for (int r = 0; r < 4; ++r) {
                const int o = w * 16 + q * 4 + r;
                out[(((size_t)b * COUT + o) * H + ho) * W + wo] =
                    acc[nt][r] + bias[o];
            }
        }
    }
}

// ---------- fallback (direct, no workspace) ----------
__global__ __launch_bounds__(256) void mdcn_direct_kernel(
    const float* __restrict__ x, const float* __restrict__ offset,
    const float* __restrict__ mask, const float* __restrict__ wsrc,
    const float* __restrict__ bias, float* __restrict__ out) {
    const int p  = blockIdx.x * blockDim.x + threadIdx.x;
    const int wo = p & (W - 1);
    const int ho = (p >> 7) & (H - 1);
    const int b  = p >> 14;
    float acc[COUT];
#pragma unroll
    for (int o = 0; o < COUT; ++o) acc[o] = bias[o];
    const float* xb = x + b * C * HW;
    for (int k = 0; k < K2; ++k) {
        const int ky = k / 3, kx = k % 3;
        const float dx = offset[((b * 2 * K2 + 2 * k    ) * H + ho) * W + wo];
        const float dy = offset[((b * 2 * K2 + 2 * k + 1) * H + ho) * W + wo];
        const float m  = mask  [((b * K2     + k        ) * H + ho) * W + wo];
        const float py = (float)(ho - 1 + ky) + dy;
        const float px = (float)(wo - 1 + kx) + dx;
        const float y0f = floorf(py), x0f = floorf(px);
        const float wy1 = py - y0f, wx1 = px - x0f;
        const float wy0 = 1.0f - wy1, wx0 = 1.0f - wx1;
        const int iy0 = (int)y0f, ix0 = (int)x0f;
        const int iy1 = iy0 + 1, ix1 = ix0 + 1;
        const bool vy0 = (iy0 >= 0) & (iy0 < H);
        const bool vy1 = (iy1 >= 0) & (iy1 < H);
        const bool vx0 = (ix0 >= 0) & (ix0 < W);
        const bool vx1 = (ix1 >= 0) & (ix1 < W);
        const float w00 = (vy0 & vx0) ? wy0 * wx0 * m : 0.0f;
        const float w01 = (vy0 & vx1) ? wy0 * wx1 * m : 0.0f;
        const float w10 = (vy1 & vx0) ? wy1 * wx0 * m : 0.0f;
        const float w11 = (vy1 & vx1) ? wy1 * wx1 * m : 0.0f;
        const int cy0 = min(max(iy0, 0), H - 1);
        const int cy1 = min(max(iy1, 0), H - 1);
        const int cx0 = min(max(ix0, 0), W - 1);
        const int cx1 = min(max(ix1, 0), W - 1);
        const int o00 = cy0 * W + cx0, o01 = cy0 * W + cx1;
        const int o10 = cy1 * W + cx0, o11 = cy1 * W + cx1;
        for (int c = 0; c < C; ++c) {
            const float* xp = xb + c * HW;
            const float val = w00 * xp[o00] + w01 * xp[o01] +
                              w10 * xp[o10] + w11 * xp[o11];
#pragma unroll
            for (int o = 0; o < COUT; ++o)
                acc[o] += wsrc[(o * C + c) * K2 + k] * val;
        }
    }
    float* op = out + ((size_t)b * COUT) * HW + ho * W + wo;
#pragma unroll
    for (int o = 0; o < COUT; ++o) op[o * HW] = acc[o];
}

extern "C" void kernel_launch(void* const* d_in, const int* in_sizes, int n_in,
                              void* d_out, int out_size, void* d_ws, size_t ws_size,
                              hipStream_t stream) {
    const float* x      = (const float*)d_in[0];
    const float* offset = (const float*)d_in[1];
    const float* mask   = (const float*)d_in[2];
    const float* weight = (const float*)d_in[3];
    const float* bias   = (const float*)d_in[4];
    float* out          = (float*)d_out;

    const size_t xt_bytes = (size_t)B * HW * C * sizeof(short);   // 16.78 MB
    const size_t wf_bytes = (size_t)COUT * C * K2 * sizeof(short);
    if (ws_size >= xt_bytes + wf_bytes) {
        short* xt    = (short*)d_ws;
        short* wfrag = (short*)((char*)d_ws + xt_bytes);
        transpose_x_kernel<<<B * (HW / 64), 256, 0, stream>>>(x, xt);
        pack_w_kernel<<<(COUT * C * K2 + 255) / 256, 256, 0, stream>>>(weight, wfrag);
        mdcn_pc_kernel<<<2 * B * H, 512, 0, stream>>>(xt, offset, mask, wfrag, bias, out);
    } else {
        mdcn_direct_kernel<<<(B * HW) / 256, 256, 0, stream>>>(
            x, offset, mask, weight, bias, out);
    }
}